// Round 4
// baseline (28711.945 us; speedup 1.0000x reference)
//
#include <hip/hip_runtime.h>
#include <stdint.h>

// VectorQuantizer: bf16-MFMA screen (A-in-registers, K-split) + exact fp32 rescore.
// Exact semantics (proven R2/R3): d = fl(fl(s_z_pairwise + s_w_pairwise) - 2*dot_f32),
// argmin with lowest-index tie-break, implemented as global atomicMin on
// (encf(d)<<32)|k. Screen maximizes raw bf16 dot (s_w <= 1.6e-6 folded into margin).

constexpr int N = 32768;
constexpr int K = 8192;
constexpr int D = 256;
constexpr int CAP = 12;
#define MARGIN 2.5e-4f

typedef __attribute__((ext_vector_type(8))) short short8v;
typedef __attribute__((ext_vector_type(4))) float float4v;

__device__ inline short f2bf(float f) {            // RNE float->bf16
    unsigned u = __float_as_uint(f);
    unsigned r = (u + 0x7FFFu + ((u >> 16) & 1u)) >> 16;
    return (short)r;
}
__device__ inline unsigned encf(float x) {         // order-preserving f32->u32
    unsigned u = __float_as_uint(x);
    return (u & 0x80000000u) ? ~u : (u | 0x80000000u);
}
__device__ inline float decf(unsigned e) {
    unsigned u = (e & 0x80000000u) ? (e & 0x7FFFFFFFu) : ~e;
    return __uint_as_float(u);
}
__device__ inline void load_lds16(const void* g, void* l) {
    __builtin_amdgcn_global_load_lds(
        (const __attribute__((address_space(1))) void*)g,
        (__attribute__((address_space(3))) void*)l, 16, 0, 0);
}

// ------------------------------------------------------------ init ---------
__global__ __launch_bounds__(256) void init_kernel(unsigned long long* __restrict__ best,
                                                   unsigned char* __restrict__ flags) {
    int i = blockIdx.x * 256 + threadIdx.x;
    best[i] = 0xFFFFFFFFFFFFFFFFull;
    flags[i] = 0;
}

// ---------------------------------------------- fused repack + rowsq -------
// 64 rows/block. Phase1: stage raw f32 rows. Phase2a: numpy-pairwise sum of
// squares (contract-proof via __fmul_rn/__fadd_rn; squares rounded
// individually — PROVEN semantics from R2). Phase2b: bf16 MFMA-fragment
// repack: chunk[row16][s] holds X[row16*16 + (lane&15)][s*32+(lane>>4)*8+j].
__global__ __launch_bounds__(256) void fuse_pack(const float* __restrict__ X,
                                                 short* __restrict__ Xf,
                                                 float* __restrict__ s_out) {
    __shared__ float raw[64][260];
    const int t = threadIdx.x;
    const size_t base = (size_t)blockIdx.x * 64 * D;
#pragma unroll
    for (int it = 0; it < 16; ++it) {
        int idx = it * 256 + t;
        int r = idx >> 6, c = idx & 63;
        float4 v = ((const float4*)(X + base))[idx];
        *(float4*)&raw[r][c * 4] = v;
    }
    __syncthreads();
    if (t < 64) {
        const float* p = raw[t];
        float tot = 0.f;
        for (int h = 0; h < 2; ++h) {
            const float* ph = p + h * 128;
            float r8[8];
#pragma unroll
            for (int j = 0; j < 8; ++j) r8[j] = __fmul_rn(ph[j], ph[j]);
            for (int i = 8; i < 128; i += 8)
#pragma unroll
                for (int j = 0; j < 8; ++j)
                    r8[j] = __fadd_rn(r8[j], __fmul_rn(ph[i + j], ph[i + j]));
            float res = __fadd_rn(__fadd_rn(__fadd_rn(r8[0], r8[1]), __fadd_rn(r8[2], r8[3])),
                                  __fadd_rn(__fadd_rn(r8[4], r8[5]), __fadd_rn(r8[6], r8[7])));
            tot = (h == 0) ? res : __fadd_rn(tot, res);
        }
        s_out[blockIdx.x * 64 + t] = tot;
    }
    // repack: wave w -> local row16 group w
    const int lane = t & 63, w = t >> 6, l4 = lane >> 4, l15 = lane & 15;
    const int row = w * 16 + l15;
#pragma unroll
    for (int s = 0; s < 8; ++s) {
        const float* src = &raw[row][s * 32 + l4 * 8];
        float4 v0 = *(const float4*)src;
        float4 v1 = *(const float4*)(src + 4);
        short8v o;
        o[0] = f2bf(v0.x); o[1] = f2bf(v0.y); o[2] = f2bf(v0.z); o[3] = f2bf(v0.w);
        o[4] = f2bf(v1.x); o[5] = f2bf(v1.y); o[6] = f2bf(v1.z); o[7] = f2bf(v1.w);
        *(short8v*)(Xf + ((size_t)(blockIdx.x * 4 + w) * 8 + s) * 512 + lane * 8) = o;
    }
}

// ------------------------------------------------------------- screen ------
// grid 512 = 128 row-groups x 4 K-quarters. Block: 4 waves; wave w owns rows
// n0 + w*64 (A frags resident in 128 VGPR). B: 64-col tiles staged to LDS.
__global__ __launch_bounds__(256, 2) void vq_screen(
    const short* __restrict__ Zf, const short* __restrict__ Wf,
    const float* __restrict__ s_w, const float* __restrict__ s_z,
    const float* __restrict__ Z, const float* __restrict__ W,
    unsigned long long* __restrict__ best, unsigned char* __restrict__ gflags)
{
    __shared__ short Bs[4][8][512];          // [col16 group][s][lane*8]
    __shared__ unsigned rowmax[256];         // encoded running row max (dot)
    __shared__ unsigned ccnt[256];
    __shared__ int candk[256][CAP];

    const int t = threadIdx.x, w = t >> 6, lane = t & 63;
    const int l4 = lane >> 4, l15 = lane & 15;
    const int q = blockIdx.x & 3, rg = blockIdx.x >> 2;
    const int n0 = rg * 256;
    const int kq0 = q * 2048;

    rowmax[t] = 0u;                          // encf(-inf) ~ 0
    ccnt[t] = 0u;

    // A resident: af[i][s] for rows (n0 + w*64 + i*16) .. +16
    short8v af[4][8];
    {
        const int R = (n0 >> 4) + w * 4;
#pragma unroll
        for (int g = 0; g < 4; ++g)
#pragma unroll
            for (int s = 0; s < 8; ++s)
                af[g][s] = *(const short8v*)(Zf + ((size_t)(R + g) * 8 + s) * 512 + lane * 8);
    }

    float maxv[16];
#pragma unroll
    for (int i = 0; i < 16; ++i) maxv[i] = -1e30f;

    for (int kt = 0; kt < 32; ++kt) {
        __syncthreads();                     // previous tile's readers done
        {   // wave w stages col16-group w (8 chunks of 1KB)
            const int col16 = (kq0 >> 4) + kt * 4 + w;
            const short* gB = Wf + (size_t)col16 * 8 * 512 + lane * 8;
#pragma unroll
            for (int s = 0; s < 8; ++s)
                load_lds16(gB + s * 512, &Bs[w][s][0]);
        }
        __syncthreads();                     // staging drained

        float4v acc[4][4];
#pragma unroll
        for (int i = 0; i < 4; ++i)
#pragma unroll
            for (int j = 0; j < 4; ++j)
#pragma unroll
                for (int r = 0; r < 4; ++r) acc[i][j][r] = 0.f;

#pragma unroll
        for (int s = 0; s < 8; ++s) {
            short8v bf[4];
#pragma unroll
            for (int j = 0; j < 4; ++j)
                bf[j] = *(const short8v*)&Bs[j][s][lane * 8];
#pragma unroll
            for (int i = 0; i < 4; ++i)
#pragma unroll
                for (int j = 0; j < 4; ++j)
                    acc[i][j] = __builtin_amdgcn_mfma_f32_16x16x32_bf16(af[i][s], bf[j], acc[i][j], 0, 0, 0);
        }

        // epilogue: maximize dot; record k within MARGIN of running row max
        const int kb = kq0 + kt * 64 + l15;
#pragma unroll
        for (int i = 0; i < 4; ++i) {
#pragma unroll
            for (int r = 0; r < 4; ++r) {
                const int slot = i * 4 + r;
                const int rowL = w * 64 + i * 16 + l4 * 4 + r;
                float v0 = acc[i][0][r], v1 = acc[i][1][r];
                float v2 = acc[i][2][r], v3 = acc[i][3][r];
                float mj = fmaxf(fmaxf(v0, v1), fmaxf(v2, v3));
                if (mj > maxv[slot]) {
                    maxv[slot] = mj;
                    atomicMax(&rowmax[rowL], encf(mj));
                }
                float th = maxv[slot] - MARGIN;
                if (mj >= th) {
                    if (v0 >= th) { unsigned c = atomicAdd(&ccnt[rowL], 1u); if (c < CAP) candk[rowL][c] = kb; }
                    if (v1 >= th) { unsigned c = atomicAdd(&ccnt[rowL], 1u); if (c < CAP) candk[rowL][c] = kb + 16; }
                    if (v2 >= th) { unsigned c = atomicAdd(&ccnt[rowL], 1u); if (c < CAP) candk[rowL][c] = kb + 32; }
                    if (v3 >= th) { unsigned c = atomicAdd(&ccnt[rowL], 1u); if (c < CAP) candk[rowL][c] = kb + 48; }
                }
            }
        }
        if ((kt & 3) == 3) {                 // refresh own bound from shared max
#pragma unroll
            for (int slot = 0; slot < 16; ++slot) {
                const int rowL = w * 64 + (slot >> 2) * 16 + l4 * 4 + (slot & 3);
                maxv[slot] = fmaxf(maxv[slot], decf(rowmax[rowL]));
            }
        }
    }

    __syncthreads();
    // exact fp32 rescore (R2-proven formula), submit via global atomicMin
    {
        const int n = n0 + t;
        unsigned cnt = ccnt[t];
        if (cnt > (unsigned)CAP) {
            gflags[n] = 1;                   // overflow -> full-row fallback
        } else {
            const float sz = s_z[n];
            const float4* zr = (const float4*)(Z + (size_t)n * D);
            float bd = 1e30f; int bk = 0x7FFFFFFF;
            for (unsigned c = 0; c < cnt; ++c) {
                const int k = candk[t][c];
                const float4* wr = (const float4*)(W + (size_t)k * D);
                float ax = 0.f, ay = 0.f, az = 0.f, aw = 0.f;
                for (int qq = 0; qq < 64; ++qq) {
                    float4 zv = zr[qq], wv = wr[qq];
                    ax = fmaf(zv.x, wv.x, ax);
                    ay = fmaf(zv.y, wv.y, ay);
                    az = fmaf(zv.z, wv.z, az);
                    aw = fmaf(zv.w, wv.w, aw);
                }
                float dot = (ax + ay) + (az + aw);
                float dd = (sz + s_w[k]) - 2.0f * dot;
                if (dd < bd || (dd == bd && k < bk)) { bd = dd; bk = k; }
            }
            if (cnt > 0)
                atomicMin(&best[n], ((unsigned long long)encf(bd) << 32) | (unsigned)bk);
        }
    }
}

// ------------------------------------------------------------ fallback -----
__global__ __launch_bounds__(256) void vq_fallback(
    const float* __restrict__ Z, const float* __restrict__ W,
    const float* __restrict__ s_z, const float* __restrict__ s_w,
    const unsigned char* __restrict__ flags, unsigned long long* __restrict__ best)
{
    __shared__ int anyf;
    const int t = threadIdx.x;
    const int rbase = blockIdx.x * 64;
    if (t == 0) anyf = 0;
    __syncthreads();
    if (t < 64 && flags[rbase + t]) anyf = 1;
    __syncthreads();
    if (!anyf) return;
    for (int r = 0; r < 64; ++r) {
        if (!flags[rbase + r]) continue;
        const int n = rbase + r;
        const float sz = s_z[n];
        const float4* zr = (const float4*)(Z + (size_t)n * D);
        float bd = 1e30f; int bk = 0x7FFFFFFF;
        for (int k = t; k < K; k += 256) {
            const float4* wr = (const float4*)(W + (size_t)k * D);
            float ax = 0.f, ay = 0.f, az = 0.f, aw = 0.f;
            for (int qq = 0; qq < 64; ++qq) {
                float4 zv = zr[qq], wv = wr[qq];
                ax = fmaf(zv.x, wv.x, ax);
                ay = fmaf(zv.y, wv.y, ay);
                az = fmaf(zv.z, wv.z, az);
                aw = fmaf(zv.w, wv.w, aw);
            }
            float dd = (sz + s_w[k]) - 2.0f * ((ax + ay) + (az + aw));
            if (dd < bd || (dd == bd && k < bk)) { bd = dd; bk = k; }
        }
        atomicMin(&best[n], ((unsigned long long)encf(bd) << 32) | (unsigned)bk);
    }
}

// ----------------------------------------------------------- outputs -------
__global__ __launch_bounds__(256) void out_kernel(const float* __restrict__ W,
                                                  const unsigned long long* __restrict__ best,
                                                  float* __restrict__ zq,
                                                  float* __restrict__ idx_f,
                                                  float* __restrict__ loss) {
    int r = blockIdx.x * 4 + (threadIdx.x >> 6);
    int lane = threadIdx.x & 63;
    int k = (int)(unsigned)(best[r] & 0xFFFFFFFFull);
    float4 v = ((const float4*)(W + (size_t)k * D))[lane];
    ((float4*)(zq + (size_t)r * D))[lane] = v;
    if (lane == 0) {
        idx_f[r] = (float)k;
        loss[r] = 0.f;
    }
}

// ------------------------------------------------------------ launch -------
extern "C" void kernel_launch(void* const* d_in, const int* in_sizes, int n_in,
                              void* d_out, int out_size, void* d_ws, size_t ws_size,
                              hipStream_t stream) {
    const float* Z = (const float*)d_in[0];
    const float* W = (const float*)d_in[1];

    float* zq    = (float*)d_out;                                  // [N, D]
    float* idx_f = zq + (size_t)N * D;                             // [N]
    float* loss  = idx_f + N;                                      // [N]

    // bf16 fragment arrays live in the not-yet-written zq region (20MB < 32MB)
    short* Zf = (short*)d_out;                                     // 16 MB
    short* Wf = (short*)((char*)d_out + (size_t)16 * 1024 * 1024); // 4 MB

    float* s_w = (float*)d_ws;                                     // 32 KB
    float* s_z = s_w + K;                                          // 128 KB
    unsigned long long* best = (unsigned long long*)(s_z + N);     // 256 KB
    unsigned char* flags = (unsigned char*)(best + N);             // 32 KB

    init_kernel<<<N / 256, 256, 0, stream>>>(best, flags);
    fuse_pack<<<N / 64, 256, 0, stream>>>(Z, Zf, s_z);
    fuse_pack<<<K / 64, 256, 0, stream>>>(W, Wf, s_w);
    vq_screen<<<512, 256, 0, stream>>>(Zf, Wf, s_w, s_z, Z, W, best, flags);
    vq_fallback<<<N / 64, 256, 0, stream>>>(Z, W, s_z, s_w, flags, best);
    out_kernel<<<N / 4, 256, 0, stream>>>(W, best, zq, idx_f, loss);
}

// Round 5
// 629.553 us; speedup vs baseline: 45.6069x; 45.6069x over previous
//
#include <hip/hip_runtime.h>
#include <stdint.h>

// VectorQuantizer: bf16-MFMA screen (A-in-registers, K-split, warmup-seeded
// margin recording) + exact fp32 rescore.
// Exact semantics (proven R2/R3/R4): d = fl(fl(s_z_pairwise + s_w_pairwise) - 2*dot_f32),
// argmin with lowest-index tie-break == global atomicMin on (encf(d)<<32)|k.
// Screen maximizes raw bf16 dot; margin (dot-space) covers bf16 err (~50sigma),
// ref fp32 quantization (1.5e-5), s_w spread (2e-7).

constexpr int N = 32768;
constexpr int K = 8192;
constexpr int D = 256;
constexpr int CAP = 16;
#define MARGIN 1.0e-4f

typedef __attribute__((ext_vector_type(8))) short short8v;
typedef __attribute__((ext_vector_type(4))) float float4v;

__device__ inline short f2bf(float f) {            // RNE float->bf16
    unsigned u = __float_as_uint(f);
    unsigned r = (u + 0x7FFFu + ((u >> 16) & 1u)) >> 16;
    return (short)r;
}
__device__ inline unsigned encf(float x) {         // order-preserving f32->u32
    unsigned u = __float_as_uint(x);
    return (u & 0x80000000u) ? ~u : (u | 0x80000000u);
}
__device__ inline float decf(unsigned e) {
    unsigned u = (e & 0x80000000u) ? (e & 0x7FFFFFFFu) : ~e;
    return __uint_as_float(u);
}
__device__ inline void load_lds16(const void* g, void* l) {
    __builtin_amdgcn_global_load_lds(
        (const __attribute__((address_space(1))) void*)g,
        (__attribute__((address_space(3))) void*)l, 16, 0, 0);
}

// ------------------------------------------------------------ init ---------
__global__ __launch_bounds__(256) void init_kernel(unsigned long long* __restrict__ best,
                                                   unsigned char* __restrict__ flags) {
    int i = blockIdx.x * 256 + threadIdx.x;
    best[i] = 0xFFFFFFFFFFFFFFFFull;
    flags[i] = 0;
}

// ---------------------------------------------- fused repack + rowsq -------
__global__ __launch_bounds__(256) void fuse_pack(const float* __restrict__ X,
                                                 short* __restrict__ Xf,
                                                 float* __restrict__ s_out) {
    __shared__ float raw[64][260];
    const int t = threadIdx.x;
    const size_t base = (size_t)blockIdx.x * 64 * D;
#pragma unroll
    for (int it = 0; it < 16; ++it) {
        int idx = it * 256 + t;
        int r = idx >> 6, c = idx & 63;
        float4 v = ((const float4*)(X + base))[idx];
        *(float4*)&raw[r][c * 4] = v;
    }
    __syncthreads();
    if (t < 64) {   // numpy pairwise sum-of-squares (PROVEN R2) — do not touch
        const float* p = raw[t];
        float tot = 0.f;
        for (int h = 0; h < 2; ++h) {
            const float* ph = p + h * 128;
            float r8[8];
#pragma unroll
            for (int j = 0; j < 8; ++j) r8[j] = __fmul_rn(ph[j], ph[j]);
            for (int i = 8; i < 128; i += 8)
#pragma unroll
                for (int j = 0; j < 8; ++j)
                    r8[j] = __fadd_rn(r8[j], __fmul_rn(ph[i + j], ph[i + j]));
            float res = __fadd_rn(__fadd_rn(__fadd_rn(r8[0], r8[1]), __fadd_rn(r8[2], r8[3])),
                                  __fadd_rn(__fadd_rn(r8[4], r8[5]), __fadd_rn(r8[6], r8[7])));
            tot = (h == 0) ? res : __fadd_rn(tot, res);
        }
        s_out[blockIdx.x * 64 + t] = tot;
    }
    // bf16 MFMA-fragment repack: chunk[row16][s][lane] = X[row16*16+(lane&15)][s*32+(lane>>4)*8+j]
    const int lane = t & 63, w = t >> 6, l4 = lane >> 4, l15 = lane & 15;
    const int row = w * 16 + l15;
#pragma unroll
    for (int s = 0; s < 8; ++s) {
        const float* src = &raw[row][s * 32 + l4 * 8];
        float4 v0 = *(const float4*)src;
        float4 v1 = *(const float4*)(src + 4);
        short8v o;
        o[0] = f2bf(v0.x); o[1] = f2bf(v0.y); o[2] = f2bf(v0.z); o[3] = f2bf(v0.w);
        o[4] = f2bf(v1.x); o[5] = f2bf(v1.y); o[6] = f2bf(v1.z); o[7] = f2bf(v1.w);
        *(short8v*)(Xf + ((size_t)(blockIdx.x * 4 + w) * 8 + s) * 512 + lane * 8) = o;
    }
}

// ------------------------------------------------------------- screen ------
// grid 512 = 128 row-groups x 4 K-quarters. Block: 4 waves; wave w owns rows
// n0+w*64 (A frags in 128 VGPR). B: 64-col tiles staged via global_load_lds.
// Phase 0: 4 max-only warmup tiles (seeds row bound at ~M_256 -> expected
// records/row-quarter ~4 << CAP=16). Phase 1: all 32 tiles with recording.
__global__ __launch_bounds__(256, 2) void vq_screen(
    const short* __restrict__ Zf, const short* __restrict__ Wf,
    const float* __restrict__ s_w, const float* __restrict__ s_z,
    const float* __restrict__ Z, const float* __restrict__ W,
    unsigned long long* __restrict__ best, unsigned char* __restrict__ gflags)
{
    __shared__ short Bs[4][8][512];
    __shared__ unsigned rowmax[256];
    __shared__ unsigned ccnt[256];
    __shared__ int   candk[256][CAP];
    __shared__ float candm[256][CAP];

    const int t = threadIdx.x, w = t >> 6, lane = t & 63;
    const int l4 = lane >> 4, l15 = lane & 15;
    const int q = blockIdx.x & 3, rg = blockIdx.x >> 2;
    const int n0 = rg * 256;
    const int kq0 = q * 2048;

    rowmax[t] = encf(-1e30f);
    ccnt[t] = 0u;

    short8v af[4][8];
    {
        const int R = (n0 >> 4) + w * 4;
#pragma unroll
        for (int g = 0; g < 4; ++g)
#pragma unroll
            for (int s = 0; s < 8; ++s)
                af[g][s] = *(const short8v*)(Zf + ((size_t)(R + g) * 8 + s) * 512 + lane * 8);
    }

    float maxv[16];
#pragma unroll
    for (int i = 0; i < 16; ++i) maxv[i] = -1e30f;

    for (int pass = 0; pass < 2; ++pass) {
        const int ntiles = pass == 0 ? 4 : 32;
        for (int kt = 0; kt < ntiles; ++kt) {
            __syncthreads();
            {   // wave w stages col16-group w
                const int col16 = (kq0 >> 4) + kt * 4 + w;
                const short* gB = Wf + (size_t)col16 * 8 * 512 + lane * 8;
#pragma unroll
                for (int s = 0; s < 8; ++s)
                    load_lds16(gB + s * 512, &Bs[w][s][0]);
            }
            __syncthreads();

            float4v acc[4][4];
#pragma unroll
            for (int i = 0; i < 4; ++i)
#pragma unroll
                for (int j = 0; j < 4; ++j)
#pragma unroll
                    for (int r = 0; r < 4; ++r) acc[i][j][r] = 0.f;

#pragma unroll
            for (int s = 0; s < 8; ++s) {
                short8v bf[4];
#pragma unroll
                for (int j = 0; j < 4; ++j)
                    bf[j] = *(const short8v*)&Bs[j][s][lane * 8];
#pragma unroll
                for (int i = 0; i < 4; ++i)
#pragma unroll
                    for (int j = 0; j < 4; ++j)
                        acc[i][j] = __builtin_amdgcn_mfma_f32_16x16x32_bf16(af[i][s], bf[j], acc[i][j], 0, 0, 0);
            }

            if (pass == 0) {                 // warmup: max only
#pragma unroll
                for (int i = 0; i < 4; ++i)
#pragma unroll
                    for (int r = 0; r < 4; ++r) {
                        const int slot = i * 4 + r;
                        float mj = fmaxf(fmaxf(acc[i][0][r], acc[i][1][r]),
                                         fmaxf(acc[i][2][r], acc[i][3][r]));
                        if (mj > maxv[slot]) {
                            maxv[slot] = mj;
                            atomicMax(&rowmax[w * 64 + i * 16 + l4 * 4 + r], encf(mj));
                        }
                    }
                continue;
            }

            // recording pass: refresh bound from shared, then record
#pragma unroll
            for (int slot = 0; slot < 16; ++slot) {
                const int rowL = w * 64 + (slot >> 2) * 16 + l4 * 4 + (slot & 3);
                maxv[slot] = fmaxf(maxv[slot], decf(rowmax[rowL]));
            }
            const int kb = kq0 + kt * 64 + l15;
#pragma unroll
            for (int i = 0; i < 4; ++i) {
#pragma unroll
                for (int r = 0; r < 4; ++r) {
                    const int slot = i * 4 + r;
                    const int rowL = w * 64 + i * 16 + l4 * 4 + r;
                    float v0 = acc[i][0][r], v1 = acc[i][1][r];
                    float v2 = acc[i][2][r], v3 = acc[i][3][r];
                    float mj = fmaxf(fmaxf(v0, v1), fmaxf(v2, v3));
                    if (mj > maxv[slot]) {
                        maxv[slot] = mj;
                        atomicMax(&rowmax[rowL], encf(mj));
                    }
                    float th = maxv[slot] - MARGIN;
                    if (mj >= th) {
                        if (v0 >= th) { unsigned c = atomicAdd(&ccnt[rowL], 1u); if (c < CAP) { candk[rowL][c] = kb;      candm[rowL][c] = v0; } }
                        if (v1 >= th) { unsigned c = atomicAdd(&ccnt[rowL], 1u); if (c < CAP) { candk[rowL][c] = kb + 16; candm[rowL][c] = v1; } }
                        if (v2 >= th) { unsigned c = atomicAdd(&ccnt[rowL], 1u); if (c < CAP) { candk[rowL][c] = kb + 32; candm[rowL][c] = v2; } }
                        if (v3 >= th) { unsigned c = atomicAdd(&ccnt[rowL], 1u); if (c < CAP) { candk[rowL][c] = kb + 48; candm[rowL][c] = v3; } }
                    }
                }
            }
        }
    }

    __syncthreads();
    // exact fp32 rescore of non-stale survivors; submit via global atomicMin
    {
        const int n = n0 + t;
        unsigned cnt = ccnt[t];
        if (cnt > (unsigned)CAP) {
            gflags[n] = 1;                   // overflow -> full-row fallback
        } else if (cnt > 0) {
            const float thr = decf(rowmax[t]) - MARGIN;
            const float sz = s_z[n];
            const float4* zr = (const float4*)(Z + (size_t)n * D);
            float bd = 1e30f; int bk = 0x7FFFFFFF;
            for (unsigned c = 0; c < cnt; ++c) {
                if (candm[t][c] < thr) continue;     // stale (pre-warm bound)
                const int k = candk[t][c];
                const float4* wr = (const float4*)(W + (size_t)k * D);
                float ax = 0.f, ay = 0.f, az = 0.f, aw = 0.f;
                for (int qq = 0; qq < 64; ++qq) {
                    float4 zv = zr[qq], wv = wr[qq];
                    ax = fmaf(zv.x, wv.x, ax);
                    ay = fmaf(zv.y, wv.y, ay);
                    az = fmaf(zv.z, wv.z, az);
                    aw = fmaf(zv.w, wv.w, aw);
                }
                float dot = (ax + ay) + (az + aw);
                float dd = (sz + s_w[k]) - 2.0f * dot;
                if (dd < bd || (dd == bd && k < bk)) { bd = dd; bk = k; }
            }
            atomicMin(&best[n], ((unsigned long long)encf(bd) << 32) | (unsigned)bk);
        }
    }
}

// ------------------------------------------------------------ fallback -----
__global__ __launch_bounds__(256) void vq_fallback(
    const float* __restrict__ Z, const float* __restrict__ W,
    const float* __restrict__ s_z, const float* __restrict__ s_w,
    const unsigned char* __restrict__ flags, unsigned long long* __restrict__ best)
{
    __shared__ int anyf;
    const int t = threadIdx.x;
    const int rbase = blockIdx.x * 64;
    if (t == 0) anyf = 0;
    __syncthreads();
    if (t < 64 && flags[rbase + t]) anyf = 1;
    __syncthreads();
    if (!anyf) return;
    for (int r = 0; r < 64; ++r) {
        if (!flags[rbase + r]) continue;
        const int n = rbase + r;
        const float sz = s_z[n];
        const float4* zr = (const float4*)(Z + (size_t)n * D);
        float bd = 1e30f; int bk = 0x7FFFFFFF;
        for (int k = t; k < K; k += 256) {
            const float4* wr = (const float4*)(W + (size_t)k * D);
            float ax = 0.f, ay = 0.f, az = 0.f, aw = 0.f;
            for (int qq = 0; qq < 64; ++qq) {
                float4 zv = zr[qq], wv = wr[qq];
                ax = fmaf(zv.x, wv.x, ax);
                ay = fmaf(zv.y, wv.y, ay);
                az = fmaf(zv.z, wv.z, az);
                aw = fmaf(zv.w, wv.w, aw);
            }
            float dd = (sz + s_w[k]) - 2.0f * ((ax + ay) + (az + aw));
            if (dd < bd || (dd == bd && k < bk)) { bd = dd; bk = k; }
        }
        atomicMin(&best[n], ((unsigned long long)encf(bd) << 32) | (unsigned)bk);
    }
}

// ----------------------------------------------------------- outputs -------
__global__ __launch_bounds__(256) void out_kernel(const float* __restrict__ W,
                                                  const unsigned long long* __restrict__ best,
                                                  float* __restrict__ zq,
                                                  float* __restrict__ idx_f,
                                                  float* __restrict__ loss) {
    int r = blockIdx.x * 4 + (threadIdx.x >> 6);
    int lane = threadIdx.x & 63;
    int k = (int)(unsigned)(best[r] & 0xFFFFFFFFull);
    float4 v = ((const float4*)(W + (size_t)k * D))[lane];
    ((float4*)(zq + (size_t)r * D))[lane] = v;
    if (lane == 0) {
        idx_f[r] = (float)k;
        loss[r] = 0.f;
    }
}

// ------------------------------------------------------------ launch -------
extern "C" void kernel_launch(void* const* d_in, const int* in_sizes, int n_in,
                              void* d_out, int out_size, void* d_ws, size_t ws_size,
                              hipStream_t stream) {
    const float* Z = (const float*)d_in[0];
    const float* W = (const float*)d_in[1];

    float* zq    = (float*)d_out;                                  // [N, D]
    float* idx_f = zq + (size_t)N * D;                             // [N]
    float* loss  = idx_f + N;                                      // [N]

    // bf16 fragment arrays live in the not-yet-written zq region
    short* Zf = (short*)d_out;                                     // 16 MB
    short* Wf = (short*)((char*)d_out + (size_t)16 * 1024 * 1024); // 4 MB

    float* s_w = (float*)d_ws;                                     // 32 KB
    float* s_z = s_w + K;                                          // 128 KB
    unsigned long long* best = (unsigned long long*)(s_z + N);     // 256 KB
    unsigned char* flags = (unsigned char*)(best + N);             // 32 KB

    init_kernel<<<N / 256, 256, 0, stream>>>(best, flags);
    fuse_pack<<<N / 64, 256, 0, stream>>>(Z, Zf, s_z);
    fuse_pack<<<K / 64, 256, 0, stream>>>(W, Wf, s_w);
    vq_screen<<<512, 256, 0, stream>>>(Zf, Wf, s_w, s_z, Z, W, best, flags);
    vq_fallback<<<N / 64, 256, 0, stream>>>(Z, W, s_z, s_w, flags, best);
    out_kernel<<<N / 4, 256, 0, stream>>>(W, best, zq, idx_f, loss);
}